// Round 10
// baseline (1529.333 us; speedup 1.0000x reference)
//
#include <hip/hip_runtime.h>
#include <stdint.h>

#define GDIM 96
#define VS (GDIM*GDIM*GDIM)
#define PTOT (2048*128)

typedef __attribute__((ext_vector_type(8))) short short8;
typedef __attribute__((ext_vector_type(4))) float float4v;

__device__ __forceinline__ uint16_t f2bf(float f){
  uint32_t u = __builtin_bit_cast(uint32_t, f);
  u += 0x7FFFu + ((u >> 16) & 1u);
  return (uint16_t)(u >> 16);
}
__device__ __forceinline__ float bf2f(uint16_t h){
  uint32_t u = ((uint32_t)h) << 16;
  return __builtin_bit_cast(float, u);
}
__device__ __forceinline__ float4v mfma16(uint4 a, uint4 b, float4v c){
  return __builtin_amdgcn_mfma_f32_16x16x32_bf16(
      __builtin_bit_cast(short8, a), __builtin_bit_cast(short8, b), c, 0, 0, 0);
}

// ---------------------------------------------------------------- K0: volume repack (fp32, voxel-major)
__global__ void k_pack_vol(const float* __restrict__ v0, const float* __restrict__ v1,
                           float* __restrict__ vpk){
  int vox = blockIdx.x * 256 + threadIdx.x;
  if (vox >= VS) return;
  union { float f[32]; float4 q[8]; } o;
  #pragma unroll
  for (int c = 0; c < 8; c++){
    o.f[c]      = v0[(size_t)c * VS + vox];
    o.f[8 + c]  = v1[(size_t)c * VS + vox];
    o.f[16 + c] = v0[(size_t)(8 + c) * VS + vox];
    o.f[24 + c] = v1[(size_t)(8 + c) * VS + vox];
  }
  float4* d = (float4*)(vpk + (size_t)vox * 32);
  #pragma unroll
  for (int i = 0; i < 8; i++) d[i] = o.q[i];
}

// ---------------------------------------------------------------- K1: weight packing (bf16 B-frags)
// B[k][n], k = 32*s + 8*q + j, n = 16*nt + nl; dst_uint4[(nt*KS + s)*64 + (nl + 16*q)]
// u 193..320: W1 forward B-frags split into hi/lo bf16 (for split-bf16 MFMA fwd1)
__global__ void k_pack_w(const float* __restrict__ W0, const float* __restrict__ W1,
                         const float* __restrict__ W2, const float* __restrict__ Wr0,
                         uint16_t* w2p, uint16_t* w1tp, uint16_t* w0tp,
                         uint16_t* wr0p, uint16_t* w2col,
                         uint16_t* w1fh, uint16_t* w1fl){
  int u = blockIdx.x;
  int lane = threadIdx.x; // 64
  if (u == 192){
    #pragma unroll
    for (int i = 0; i < 4; i++){
      int k = lane * 4 + i;
      w2col[k] = f2bf(W2[k * 16 + 0]);   // W2[:,0]
    }
    return;
  }
  if (u >= 193){
    int uu = u - 193;           // 0..127
    int nt = uu >> 3, s = uu & 7;
    int q = lane >> 4, nl = lane & 15;
    union { uint16_t h[8]; uint4 v; } hh, ll;
    #pragma unroll
    for (int j = 0; j < 8; j++){
      int k = 32 * s + 8 * q + j;
      int n = 16 * nt + nl;
      float v = W1[k * 256 + n];
      uint16_t hb = f2bf(v);
      hh.h[j] = hb;
      ll.h[j] = f2bf(v - bf2f(hb));
    }
    ((uint4*)w1fh)[(size_t)(nt * 8 + s) * 64 + lane] = hh.v;
    ((uint4*)w1fl)[(size_t)(nt * 8 + s) * 64 + lane] = ll.v;
    return;
  }
  const float* src; uint16_t* dst; int KSn, Kl, Nl, ustart, ld; bool tr;
  if (u < 8)        { src = W2;  dst = w2p;  KSn = 8; Kl = 256; Nl = 16;  tr = false; ustart = 0;   ld = 16;  }
  else if (u < 136) { src = W1;  dst = w1tp; KSn = 8; Kl = 256; Nl = 256; tr = true;  ustart = 8;   ld = 256; } // B=W1^T
  else if (u < 160) { src = W0;  dst = w0tp; KSn = 8; Kl = 256; Nl = 35;  tr = true;  ustart = 136; ld = 256; } // B=W0^T
  else              { src = Wr0; dst = wr0p; KSn = 2; Kl = 56;  Nl = 256; tr = false; ustart = 160; ld = 256; }
  int uu = u - ustart;
  int nt = uu / KSn, s = uu % KSn;
  int q = lane >> 4, nl = lane & 15;
  union { uint16_t h[8]; uint4 v; } vals;
  #pragma unroll
  for (int j = 0; j < 8; j++){
    int k = 32 * s + 8 * q + j;
    int n = 16 * nt + nl;
    float v = 0.f;
    if (k < Kl && n < Nl) v = tr ? src[n * ld + k] : src[k * ld + n];
    vals.h[j] = f2bf(v);
  }
  ((uint4*)dst)[(size_t)(nt * KSn + s) * 64 + lane] = vals.v;
}

// ---------------------------------------------------------------- K2: trilinear sampling -> feat f32 [chunk][32]
__global__ void k_sample(const float* __restrict__ pts, const float* __restrict__ vpk,
                         float* __restrict__ feat, int base, int chunk){
  int idx = blockIdx.x * 256 + threadIdx.x;
  if (idx >= chunk) return;
  int g = base + idx;
  float px = pts[(size_t)g * 3 + 0], py = pts[(size_t)g * 3 + 1], pz = pts[(size_t)g * 3 + 2];
  float x = fminf(fmaxf(px * 95.f, 0.f), 94.9999f);
  float y = fminf(fmaxf(py * 95.f, 0.f), 94.9999f);
  float z = fminf(fmaxf(pz * 95.f, 0.f), 94.9999f);
  int ix = (int)x, iy = (int)y, iz = (int)z;
  float fx = x - ix, fy = y - iy, fz = z - iz;
  float acc[32];
  #pragma unroll
  for (int c = 0; c < 32; c++) acc[c] = 0.f;
  size_t cbase = ((size_t)(iz * GDIM + iy) * GDIM + ix) * 32;
  #pragma unroll
  for (int dz = 0; dz < 2; dz++)
  #pragma unroll
  for (int dy = 0; dy < 2; dy++)
  #pragma unroll
  for (int dx = 0; dx < 2; dx++){
    float w = (dx ? fx : 1.f - fx) * (dy ? fy : 1.f - fy) * (dz ? fz : 1.f - fz);
    const float4* cp = (const float4*)(vpk + cbase + ((size_t)(dz * GDIM + dy) * GDIM + dx) * 32);
    #pragma unroll
    for (int qq = 0; qq < 8; qq++){
      float4 v = cp[qq];
      acc[qq*4+0] += w * v.x; acc[qq*4+1] += w * v.y;
      acc[qq*4+2] += w * v.z; acc[qq*4+3] += w * v.w;
    }
  }
  float4* fp = (float4*)(feat + (size_t)idx * 32);
  #pragma unroll
  for (int qq = 0; qq < 8; qq++){
    float4 v = {acc[qq*4+0], acc[qq*4+1], acc[qq*4+2], acc[qq*4+3]};
    fp[qq] = v;
  }
}

// ---------------------------------------------------------------- fwd layer0, fp64: h0 = relu(x@W0+b0), mask0
// fp64 kept: h0 VALUES feed fwd1's near-zero sign decisions, so h0 must be
// fp64-value-accurate (round-4 lesson). LDS swizzled (k, j4, ng).
__launch_bounds__(256)
__global__ void k_fwd0(const float* __restrict__ pts, const float* __restrict__ feat,
                       const float* __restrict__ W0, const float* __restrict__ b0,
                       float* __restrict__ h0, uint16_t* __restrict__ mask0,
                       int base, int chunk){
  __shared__ float w0s[35 * 256];   // swizzled: [(k*4 + j4)*16 + ng] float4s
  __shared__ float xs[16][36];
  __shared__ float b0s[256];        // swizzled: [(j4*16 + ng)] float4s
  int tid = threadIdx.x;
  for (int i = tid; i < 35 * 256; i += 256){
    int k = i >> 8, n = i & 255;
    int ng = n >> 4, j4 = (n >> 2) & 3, e = n & 3;
    w0s[((k * 4 + j4) * 16 + ng) * 4 + e] = W0[i];
  }
  {
    int n = tid, ng = n >> 4, j4 = (n >> 2) & 3, e = n & 3;
    b0s[(j4 * 16 + ng) * 4 + e] = b0[n];
  }
  int p0 = blockIdx.x * 16;
  for (int i = tid; i < 16 * 35; i += 256){
    int p = i / 35, k = i - p * 35;
    float v;
    if (k < 3) v = pts[(size_t)(base + p0 + p) * 3 + k];
    else       v = feat[(size_t)(p0 + p) * 32 + (k - 3)];
    xs[p][k] = v;
  }
  __syncthreads();
  int p = tid >> 4, ng = tid & 15;
  const float4* w4 = (const float4*)w0s;
  const float4* b4 = (const float4*)b0s;
  double acc[16];
  #pragma unroll
  for (int j4 = 0; j4 < 4; j4++){
    float4 b = b4[j4 * 16 + ng];
    acc[j4*4+0] = (double)b.x;
    acc[j4*4+1] = (double)b.y;
    acc[j4*4+2] = (double)b.z;
    acc[j4*4+3] = (double)b.w;
  }
  for (int k = 0; k < 35; k++){
    double xv = (double)xs[p][k];
    #pragma unroll
    for (int j4 = 0; j4 < 4; j4++){
      float4 w = w4[(k * 4 + j4) * 16 + ng];
      acc[j4*4+0] += xv * (double)w.x;
      acc[j4*4+1] += xv * (double)w.y;
      acc[j4*4+2] += xv * (double)w.z;
      acc[j4*4+3] += xv * (double)w.w;
    }
  }
  uint32_t m = 0;
  float* hp = h0 + (size_t)(p0 + p) * 256 + ng * 16;
  #pragma unroll
  for (int j4 = 0; j4 < 4; j4++){
    float4 v;
    v.x = fmaxf((float)acc[j4*4+0], 0.f);
    v.y = fmaxf((float)acc[j4*4+1], 0.f);
    v.z = fmaxf((float)acc[j4*4+2], 0.f);
    v.w = fmaxf((float)acc[j4*4+3], 0.f);
    ((float4*)hp)[j4] = v;
  }
  #pragma unroll
  for (int j = 0; j < 16; j++) if (acc[j] > 0.0) m |= 1u << j;
  mask0[(size_t)(p0 + p) * 16 + ng] = (uint16_t)m;
}

// ---------------------------------------------------------------- FUSED: fwd1 + gemm_h + gemm_bwd2 + gemm_bwd1
// Per wave (one 16-pt tile): compute h1 A-frags in registers (r3's 3-pass
// split-bf16 + fp64 fixup, bit-identical), then consume them directly for
// h = h1@W2+b2, g0 = mask0.*((mask1.*W2col)@W1T), gx = g0@W0T.
// h1A and g0A never touch memory (saves ~130 MB/chunk + 3 launches).
// hlds is wave-private ([wv]) -> no __syncthreads needed; waves overlap freely.
__launch_bounds__(256)
__global__ void k_fused(const float* __restrict__ h0,
                        const uint16_t* __restrict__ W1FH, const uint16_t* __restrict__ W1FL,
                        const float* __restrict__ W1, const float* __restrict__ b1,
                        const uint16_t* __restrict__ W2p, const float* __restrict__ b2,
                        float* __restrict__ hout,
                        const uint16_t* __restrict__ W1Tp, const uint16_t* __restrict__ w2col,
                        const uint16_t* __restrict__ mask0,
                        const uint16_t* __restrict__ W0Tp, uint16_t* __restrict__ gx,
                        int chunk){
  __shared__ __align__(16) uint16_t hlds[4][16][280];
  int lane = threadIdx.x & 63, wv = threadIdx.x >> 6;
  int tile = blockIdx.x * 4 + wv;
  int q = lane >> 4, m = lane & 15;

  // ---- phase 1: A-frags from h0 (split f32 -> hi+lo bf16)
  uint4 ah[8], al[8];
  const float* ap = h0 + ((size_t)(tile * 16 + m)) * 256 + 8 * q;
  #pragma unroll
  for (int s = 0; s < 8; s++){
    float4 v0 = *(const float4*)(ap + 32 * s);
    float4 v1 = *(const float4*)(ap + 32 * s + 4);
    float f[8] = {v0.x, v0.y, v0.z, v0.w, v1.x, v1.y, v1.z, v1.w};
    union { uint16_t h[8]; uint4 u; } hh, ll;
    #pragma unroll
    for (int j = 0; j < 8; j++){
      uint16_t hb = f2bf(f[j]);
      hh.h[j] = hb;
      ll.h[j] = f2bf(f[j] - bf2f(hb));
    }
    ah[s] = hh.u; al[s] = ll.u;
  }

  // ---- phase 2: fwd1 (r3: 3-pass serial chain + fp64 borderline fixup) -> hlds
  {
    const uint4* bh = (const uint4*)W1FH + lane;
    const uint4* bl = (const uint4*)W1FL + lane;
    for (int nt = 0; nt < 16; nt++){
      float bv = b1[nt * 16 + m];
      float4v acc = {bv, bv, bv, bv};
      #pragma unroll
      for (int s = 0; s < 8; s++){
        uint4 BH = bh[(nt * 8 + s) * 64];
        uint4 BL = bl[(nt * 8 + s) * 64];
        acc = mfma16(ah[s], BH, acc);   // hi*hi
        acc = mfma16(al[s], BH, acc);   // lo*hi
        acc = mfma16(ah[s], BL, acc);   // hi*lo  (lo*lo ~2^-18, dropped; r3 numerics)
      }
      #pragma unroll
      for (int r = 0; r < 4; r++){
        if (fabsf(acc[r]) < 1e-5f){
          int prow = tile * 16 + 4 * q + r;
          int n = nt * 16 + m;
          double da = (double)b1[n];
          const float* hrow = h0 + (size_t)prow * 256;
          for (int k = 0; k < 256; k++)
            da += (double)hrow[k] * (double)W1[k * 256 + n];
          acc[r] = (float)da;
        }
      }
      #pragma unroll
      for (int r = 0; r < 4; r++)
        hlds[wv][4 * q + r][nt * 16 + m] = f2bf(fmaxf(acc[r], 0.f));
    }
  }
  // readout h1 A-frags (wave-private LDS; compiler orders via lgkmcnt)
  uint4 af[8];
  #pragma unroll
  for (int s = 0; s < 8; s++)
    af[s] = *(const uint4*)&hlds[wv][m][32 * s + 8 * q];

  // ---- phase 3: h = h1 @ W2 + b2 (r3 gemm_h, 2-chain)
  {
    const uint4* bp = (const uint4*)W2p + lane;
    float4v a0 = {0.f,0.f,0.f,0.f}, a1 = {0.f,0.f,0.f,0.f};
    #pragma unroll
    for (int s = 0; s < 4; s++){
      a0 = mfma16(af[s], bp[s * 64], a0);
      a1 = mfma16(af[(s + 4)], bp[(s + 4) * 64], a1);
    }
    float bv = b2[m];
    #pragma unroll
    for (int r = 0; r < 4; r++)
      hout[((size_t)(tile * 16 + 4 * q + r)) * 16 + m] = (a0[r] + a1[r]) + bv;
  }

  // ---- phase 4: masked A-frags (mask1 .* W2col) from registers (bits == r3's h1A path)
  uint4 afm[8];
  {
    const uint4* wc = (const uint4*)w2col;
    #pragma unroll
    for (int s = 0; s < 8; s++){
      union { uint4 v; uint16_t h[8]; } a, w, o;
      a.v = af[s];
      w.v = wc[s * 4 + q];
      #pragma unroll
      for (int j = 0; j < 8; j++) o.h[j] = a.h[j] ? w.h[j] : (uint16_t)0;
      afm[s] = o.v;
    }
  }

  // ---- phase 5: g0 = mask0 .* (afm @ W1T) -> hlds -> g0 A-frags (r3 bwd2)
  {
    const uint4* bp = (const uint4*)W1Tp + lane;
    for (int nt = 0; nt < 16; nt++){
      float4v a0 = {0.f,0.f,0.f,0.f}, a1 = {0.f,0.f,0.f,0.f};
      #pragma unroll
      for (int s = 0; s < 4; s++){
        a0 = mfma16(afm[s], bp[(nt * 8 + s) * 64], a0);
        a1 = mfma16(afm[s + 4], bp[(nt * 8 + s + 4) * 64], a1);
      }
      #pragma unroll
      for (int r = 0; r < 4; r++){
        uint16_t mw = mask0[((size_t)(tile * 16 + 4 * q + r)) * 16 + nt];
        float v = ((mw >> m) & 1) ? (a0[r] + a1[r]) : 0.f;
        hlds[wv][4 * q + r][nt * 16 + m] = f2bf(v);
      }
    }
  }
  uint4 gf[8];
  #pragma unroll
  for (int s = 0; s < 8; s++)
    gf[s] = *(const uint4*)&hlds[wv][m][32 * s + 8 * q];

  // ---- phase 6: gx = g0 @ W0T (r3 bwd1, 2-chain)
  {
    const uint4* bp = (const uint4*)W0Tp + lane;
    for (int nt = 0; nt < 3; nt++){
      float4v a0 = {0.f,0.f,0.f,0.f}, a1 = {0.f,0.f,0.f,0.f};
      #pragma unroll
      for (int s = 0; s < 4; s++){
        a0 = mfma16(gf[s], bp[(nt * 8 + s) * 64], a0);
        a1 = mfma16(gf[s + 4], bp[(nt * 8 + s + 4) * 64], a1);
      }
      #pragma unroll
      for (int r = 0; r < 4; r++)
        gx[((size_t)(tile * 16 + 4 * q + r)) * 48 + nt * 16 + m] = f2bf(a0[r] + a1[r]);
    }
  }
}

// ---------------------------------------------------------------- K_grad: pos-grad + pointwise outputs + rgb_in A-frags
__global__ void k_grad(const float* __restrict__ pts, const float* __restrict__ dirs,
                       const float* __restrict__ deltas, const float* __restrict__ beta,
                       const float* __restrict__ variance, const float* __restrict__ vpk,
                       const uint16_t* __restrict__ gx, const float* __restrict__ feat,
                       const float* __restrict__ hrm, uint16_t* __restrict__ rgbinA,
                       float* __restrict__ out, int base, int chunk){
  int idx = blockIdx.x * 256 + threadIdx.x;
  if (idx >= chunk) return;
  int g = base + idx;
  union { uint16_t h[48]; uint4 q[6]; } gv;
  const uint4* gp = (const uint4*)(gx + (size_t)idx * 48);
  #pragma unroll
  for (int i = 0; i < 6; i++) gv.q[i] = gp[i];
  float gfeat[32];
  #pragma unroll
  for (int c = 0; c < 32; c++) gfeat[c] = bf2f(gv.h[3 + c]);

  float px = pts[(size_t)g * 3 + 0], py = pts[(size_t)g * 3 + 1], pz = pts[(size_t)g * 3 + 2];
  float x = fminf(fmaxf(px * 95.f, 0.f), 94.9999f);
  float y = fminf(fmaxf(py * 95.f, 0.f), 94.9999f);
  float z = fminf(fmaxf(pz * 95.f, 0.f), 94.9999f);
  int ix = (int)x, iy = (int)y, iz = (int)z;
  float fx = x - ix, fy = y - iy, fz = z - iz;
  size_t cbase = ((size_t)(iz * GDIM + iy) * GDIM + ix) * 32;
  float gsx = 0.f, gsy = 0.f, gsz = 0.f;
  #pragma unroll
  for (int dz = 0; dz < 2; dz++)
  #pragma unroll
  for (int dy = 0; dy < 2; dy++)
  #pragma unroll
  for (int dx = 0; dx < 2; dx++){
    const float4* cp = (const float4*)(vpk + cbase + ((size_t)(dz * GDIM + dy) * GDIM + dx) * 32);
    float sdot = 0.f;
    #pragma unroll
    for (int qq = 0; qq < 8; qq++){
      float4 v = cp[qq];
      sdot += gfeat[qq*4+0] * v.x + gfeat[qq*4+1] * v.y
            + gfeat[qq*4+2] * v.z + gfeat[qq*4+3] * v.w;
    }
    float wx = dx ? fx : 1.f - fx, wy = dy ? fy : 1.f - fy, wz = dz ? fz : 1.f - fz;
    gsx += sdot * (dx ? 1.f : -1.f) * wy * wz;
    gsy += sdot * wx * (dy ? 1.f : -1.f) * wz;
    gsz += sdot * wx * wy * (dz ? 1.f : -1.f);
  }
  float grx = bf2f(gv.h[0]) + 95.f * gsx;
  float gry = bf2f(gv.h[1]) + 95.f * gsy;
  float grz = bf2f(gv.h[2]) + 95.f * gsz;

  float* o_dens  = out + (size_t)3 * PTOT;
  float* o_sdf   = out + (size_t)4 * PTOT;
  float* o_grad  = out + (size_t)5 * PTOT;
  float* o_norm  = out + (size_t)8 * PTOT;
  float* o_alpha = out + (size_t)11 * PTOT;

  o_grad[(size_t)g * 3 + 0] = grx;
  o_grad[(size_t)g * 3 + 1] = gry;
  o_grad[(size_t)g * 3 + 2] = grz;
  float nn = sqrtf(grx * grx + gry * gry + grz * grz);
  float inv = 1.f / fmaxf(nn, 1e-12f);
  o_norm[(size_t)g * 3 + 0] = grx * inv;
  o_norm[(size_t)g * 3 + 1] = gry * inv;
  o_norm[(size_t)g * 3 + 2] = grz * inv;

  float sdf = hrm[(size_t)idx * 16];
  o_sdf[g] = sdf;
  float be = fabsf(beta[0]) + 1e-4f;
  float sgn = (sdf > 0.f) ? 1.f : ((sdf < 0.f) ? -1.f : 0.f);
  o_dens[g] = (0.5f + 0.5f * sgn * expm1f(-fabsf(sdf) / be)) / be;

  float dxr = dirs[(size_t)g * 3 + 0], dyr = dirs[(size_t)g * 3 + 1], dzr = dirs[(size_t)g * 3 + 2];
  float delta = deltas[g];
  float inv_s = expf(variance[0] * 10.f);
  inv_s = fminf(fmaxf(inv_s, 1e-6f), 1e6f);
  float tc = dxr * grx + dyr * gry + dzr * grz;
  float itc = -fmaxf(-tc, 0.f);
  float en = sdf + itc * delta * 0.5f;
  float ep = sdf - itc * delta * 0.5f;
  float pc = 1.f / (1.f + expf(-ep * inv_s));
  float nc = 1.f / (1.f + expf(-en * inv_s));
  float alpha = (pc - nc + 1e-5f) / (pc + 1e-5f);
  o_alpha[g] = fminf(fmaxf(alpha, 0.f), 1.f);

  // rgb_in = [p(3), grad(3), feat(32), geo(15), dir(3)] -> 56, pad 64, A-frag layout
  union { uint16_t h[64]; uint4 q[8]; } rv;
  #pragma unroll
  for (int i = 0; i < 64; i++) rv.h[i] = 0;
  rv.h[0] = f2bf(px); rv.h[1] = f2bf(py); rv.h[2] = f2bf(pz);
  rv.h[3] = f2bf(grx); rv.h[4] = f2bf(gry); rv.h[5] = f2bf(grz);
  const float4* fp = (const float4*)(feat + (size_t)idx * 32);
  #pragma unroll
  for (int qq = 0; qq < 8; qq++){
    float4 v = fp[qq];
    rv.h[6 + qq*4 + 0] = f2bf(v.x); rv.h[6 + qq*4 + 1] = f2bf(v.y);
    rv.h[6 + qq*4 + 2] = f2bf(v.z); rv.h[6 + qq*4 + 3] = f2bf(v.w);
  }
  #pragma unroll
  for (int j = 0; j < 15; j++) rv.h[38 + j] = f2bf(hrm[(size_t)idx * 16 + 1 + j]);
  rv.h[53] = f2bf(dxr); rv.h[54] = f2bf(dyr); rv.h[55] = f2bf(dzr);
  int tile = idx >> 4, m = idx & 15;
  #pragma unroll
  for (int g8 = 0; g8 < 8; g8++){
    int s = g8 >> 2, qq = g8 & 3;
    ((uint4*)rgbinA)[((size_t)(tile * 2 + s)) * 64 + m + 16 * qq] = rv.q[g8];
  }
}

// ---------------------------------------------------------------- rgb: hr = relu(rgb_in@Wr0+br0); rgb = sigmoid(hr@Wr1+br1)
__launch_bounds__(256)
__global__ void k_rgb(const uint16_t* __restrict__ rgbinA, const uint16_t* __restrict__ Wr0p,
                      const float* __restrict__ br0, const float* __restrict__ Wr1,
                      const float* __restrict__ br1, float* __restrict__ outrgb,
                      int base, int chunk){
  __shared__ __align__(16) uint16_t hr[64][280];
  __shared__ float wr1s[768];
  __shared__ float br1s[3];
  int t = threadIdx.x;
  for (int i = t; i < 768; i += 256) wr1s[i] = Wr1[i];
  if (t < 3) br1s[t] = br1[t];
  int lane = t & 63, wv = t >> 6;
  int tile = blockIdx.x * 4 + wv;
  int q = lane >> 4, nl = lane & 15;
  uint4 af[2];
  const uint4* ap = (const uint4*)rgbinA + (size_t)tile * 2 * 64 + lane;
  af[0] = ap[0]; af[1] = ap[64];
  const uint4* bp = (const uint4*)Wr0p + lane;
  for (int nt = 0; nt < 16; nt++){
    float4v a0 = {0.f, 0.f, 0.f, 0.f}, a1 = {0.f, 0.f, 0.f, 0.f};
    a0 = mfma16(af[0], bp[(nt * 2) * 64], a0);
    a1 = mfma16(af[1], bp[(nt * 2 + 1) * 64], a1);
    float bv = br0[nt * 16 + nl];
    #pragma unroll
    for (int r = 0; r < 4; r++)
      hr[wv * 16 + 4 * q + r][nt * 16 + nl] = f2bf(fmaxf((a0[r] + a1[r]) + bv, 0.f));
  }
  __syncthreads();
  if (t < 192){
    int lp = t / 3, ch = t - lp * 3;
    float acc2 = 0.f;
    for (int u = 0; u < 256; u++) acc2 += bf2f(hr[lp][u]) * wr1s[u * 3 + ch];
    acc2 += br1s[ch];
    float val = 1.f / (1.f + expf(-acc2));
    outrgb[(size_t)(base + blockIdx.x * 64 + lp) * 3 + ch] = val;
  }
}

// ----------------------------------------------------------------
extern "C" void kernel_launch(void* const* d_in, const int* in_sizes, int n_in,
                              void* d_out, int out_size, void* d_ws, size_t ws_size,
                              hipStream_t stream){
  const float* pts      = (const float*)d_in[0];
  const float* dirs     = (const float*)d_in[1];
  const float* deltas   = (const float*)d_in[2];
  const float* vol0     = (const float*)d_in[3];
  const float* vol1     = (const float*)d_in[4];
  const float* W0       = (const float*)d_in[5];
  const float* b0       = (const float*)d_in[6];
  const float* W1       = (const float*)d_in[7];
  const float* b1       = (const float*)d_in[8];
  const float* W2       = (const float*)d_in[9];
  const float* b2       = (const float*)d_in[10];
  const float* Wr0      = (const float*)d_in[11];
  const float* br0      = (const float*)d_in[12];
  const float* Wr1      = (const float*)d_in[13];
  const float* br1      = (const float*)d_in[14];
  const float* beta     = (const float*)d_in[15];
  const float* variance = (const float*)d_in[16];
  float* out = (float*)d_out;
  char* ws = (char*)d_ws;

  size_t off = 0;
  auto alloc = [&](size_t b){ size_t o = off; off += (b + 255) & ~(size_t)255; return o; };
  size_t o_vpk  = alloc((size_t)VS * 32 * 4);   // fp32 voxel-major volumes (113 MB)
  size_t o_w2p  = alloc(8192);
  size_t o_w1tp = alloc(131072);
  size_t o_w0tp = alloc(24576);
  size_t o_wr0p = alloc(32768);
  size_t o_w2c  = alloc(512);
  size_t o_w1fh = alloc(131072);                // W1 forward B-frags, hi bf16
  size_t o_w1fl = alloc(131072);                // W1 forward B-frags, lo bf16
  size_t fixed = off;

  // per-point: feat 128 + h0 1024 + mask 32 + rgbinA 512 + gx 96 + hbuf 64 = 1856 B
  const int cands[7] = {262144, 131072, 65536, 32768, 16384, 8192, 4096};
  int chunk = 2048;
  for (int i = 0; i < 7; i++){
    if (fixed + (size_t)cands[i] * 1880 <= ws_size){ chunk = cands[i]; break; }
  }
  size_t o_feat = alloc((size_t)chunk * 128);
  size_t o_h0   = alloc((size_t)chunk * 1024);  // f32 h0
  size_t o_mask = alloc((size_t)chunk * 32);
  size_t o_h1A  = alloc((size_t)chunk * 512);   // rgbinA (h1A never goes to memory now)
  size_t o_gx   = alloc((size_t)chunk * 96);
  size_t o_h    = alloc((size_t)chunk * 64);

  float*    vpk  = (float*)(ws + o_vpk);
  uint16_t* w2p  = (uint16_t*)(ws + o_w2p);
  uint16_t* w1tp = (uint16_t*)(ws + o_w1tp);
  uint16_t* w0tp = (uint16_t*)(ws + o_w0tp);
  uint16_t* wr0p = (uint16_t*)(ws + o_wr0p);
  uint16_t* w2c  = (uint16_t*)(ws + o_w2c);
  uint16_t* w1fh = (uint16_t*)(ws + o_w1fh);
  uint16_t* w1fl = (uint16_t*)(ws + o_w1fl);
  float*    feat = (float*)(ws + o_feat);
  float*    h0   = (float*)(ws + o_h0);
  uint16_t* mask = (uint16_t*)(ws + o_mask);
  uint16_t* rgbinA = (uint16_t*)(ws + o_h1A);
  uint16_t* gx   = (uint16_t*)(ws + o_gx);
  float*    hbuf = (float*)(ws + o_h);

  k_pack_vol<<<(VS + 255) / 256, 256, 0, stream>>>(vol0, vol1, vpk);
  k_pack_w<<<321, 64, 0, stream>>>(W0, W1, W2, Wr0, w2p, w1tp, w0tp, wr0p, w2c, w1fh, w1fl);

  int nchunks = PTOT / chunk;
  for (int c = 0; c < nchunks; c++){
    int basep = c * chunk;
    k_sample<<<chunk / 256, 256, 0, stream>>>(pts, vpk, feat, basep, chunk);
    k_fwd0<<<chunk / 16, 256, 0, stream>>>(pts, feat, W0, b0, h0, mask, basep, chunk);
    k_fused<<<chunk / 64, 256, 0, stream>>>(h0, w1fh, w1fl, W1, b1,
                                            w2p, b2, hbuf,
                                            w1tp, w2c, mask,
                                            w0tp, gx, chunk);
    k_grad<<<chunk / 256, 256, 0, stream>>>(pts, dirs, deltas, beta, variance, vpk,
                                            gx, feat, hbuf, rgbinA, out, basep, chunk);
    k_rgb<<<chunk / 64, 256, 0, stream>>>(rgbinA, wr0p, br0, Wr1, br1, out, basep, chunk);
  }
}

// Round 12
// 1267.955 us; speedup vs baseline: 1.2061x; 1.2061x over previous
//
#include <hip/hip_runtime.h>
#include <stdint.h>

#define GDIM 96
#define VS (GDIM*GDIM*GDIM)
#define PTOT (2048*128)

typedef __attribute__((ext_vector_type(8))) short short8;
typedef __attribute__((ext_vector_type(4))) float float4v;

__device__ __forceinline__ uint16_t f2bf(float f){
  uint32_t u = __builtin_bit_cast(uint32_t, f);
  u += 0x7FFFu + ((u >> 16) & 1u);
  return (uint16_t)(u >> 16);
}
__device__ __forceinline__ float bf2f(uint16_t h){
  uint32_t u = ((uint32_t)h) << 16;
  return __builtin_bit_cast(float, u);
}
__device__ __forceinline__ float4v mfma16(uint4 a, uint4 b, float4v c){
  return __builtin_amdgcn_mfma_f32_16x16x32_bf16(
      __builtin_bit_cast(short8, a), __builtin_bit_cast(short8, b), c, 0, 0, 0);
}

// ---------------------------------------------------------------- K0: volume repack (fp32, voxel-major)
__global__ void k_pack_vol(const float* __restrict__ v0, const float* __restrict__ v1,
                           float* __restrict__ vpk){
  int vox = blockIdx.x * 256 + threadIdx.x;
  if (vox >= VS) return;
  union { float f[32]; float4 q[8]; } o;
  #pragma unroll
  for (int c = 0; c < 8; c++){
    o.f[c]      = v0[(size_t)c * VS + vox];
    o.f[8 + c]  = v1[(size_t)c * VS + vox];
    o.f[16 + c] = v0[(size_t)(8 + c) * VS + vox];
    o.f[24 + c] = v1[(size_t)(8 + c) * VS + vox];
  }
  float4* d = (float4*)(vpk + (size_t)vox * 32);
  #pragma unroll
  for (int i = 0; i < 8; i++) d[i] = o.q[i];
}

// ---------------------------------------------------------------- K1: weight packing (bf16 B-frags)
// B[k][n], k = 32*s + 8*q + j, n = 16*nt + nl; dst_uint4[(nt*KS + s)*64 + (nl + 16*q)]
// u 193..320: W1 forward B-frags split into hi/lo bf16 (for split-bf16 MFMA fwd1)
__global__ void k_pack_w(const float* __restrict__ W0, const float* __restrict__ W1,
                         const float* __restrict__ W2, const float* __restrict__ Wr0,
                         uint16_t* w2p, uint16_t* w1tp, uint16_t* w0tp,
                         uint16_t* wr0p, uint16_t* w2col,
                         uint16_t* w1fh, uint16_t* w1fl){
  int u = blockIdx.x;
  int lane = threadIdx.x; // 64
  if (u == 192){
    #pragma unroll
    for (int i = 0; i < 4; i++){
      int k = lane * 4 + i;
      w2col[k] = f2bf(W2[k * 16 + 0]);   // W2[:,0]
    }
    return;
  }
  if (u >= 193){
    int uu = u - 193;           // 0..127
    int nt = uu >> 3, s = uu & 7;
    int q = lane >> 4, nl = lane & 15;
    union { uint16_t h[8]; uint4 v; } hh, ll;
    #pragma unroll
    for (int j = 0; j < 8; j++){
      int k = 32 * s + 8 * q + j;
      int n = 16 * nt + nl;
      float v = W1[k * 256 + n];
      uint16_t hb = f2bf(v);
      hh.h[j] = hb;
      ll.h[j] = f2bf(v - bf2f(hb));
    }
    ((uint4*)w1fh)[(size_t)(nt * 8 + s) * 64 + lane] = hh.v;
    ((uint4*)w1fl)[(size_t)(nt * 8 + s) * 64 + lane] = ll.v;
    return;
  }
  const float* src; uint16_t* dst; int KSn, Kl, Nl, ustart, ld; bool tr;
  if (u < 8)        { src = W2;  dst = w2p;  KSn = 8; Kl = 256; Nl = 16;  tr = false; ustart = 0;   ld = 16;  }
  else if (u < 136) { src = W1;  dst = w1tp; KSn = 8; Kl = 256; Nl = 256; tr = true;  ustart = 8;   ld = 256; } // B=W1^T
  else if (u < 160) { src = W0;  dst = w0tp; KSn = 8; Kl = 256; Nl = 35;  tr = true;  ustart = 136; ld = 256; } // B=W0^T
  else              { src = Wr0; dst = wr0p; KSn = 2; Kl = 56;  Nl = 256; tr = false; ustart = 160; ld = 256; }
  int uu = u - ustart;
  int nt = uu / KSn, s = uu % KSn;
  int q = lane >> 4, nl = lane & 15;
  union { uint16_t h[8]; uint4 v; } vals;
  #pragma unroll
  for (int j = 0; j < 8; j++){
    int k = 32 * s + 8 * q + j;
    int n = 16 * nt + nl;
    float v = 0.f;
    if (k < Kl && n < Nl) v = tr ? src[n * ld + k] : src[k * ld + n];
    vals.h[j] = f2bf(v);
  }
  ((uint4*)dst)[(size_t)(nt * KSn + s) * 64 + lane] = vals.v;
}

// ---------------------------------------------------------------- K2: trilinear sampling -> feat f32 [chunk][32]
__global__ void k_sample(const float* __restrict__ pts, const float* __restrict__ vpk,
                         float* __restrict__ feat, int base, int chunk){
  int idx = blockIdx.x * 256 + threadIdx.x;
  if (idx >= chunk) return;
  int g = base + idx;
  float px = pts[(size_t)g * 3 + 0], py = pts[(size_t)g * 3 + 1], pz = pts[(size_t)g * 3 + 2];
  float x = fminf(fmaxf(px * 95.f, 0.f), 94.9999f);
  float y = fminf(fmaxf(py * 95.f, 0.f), 94.9999f);
  float z = fminf(fmaxf(pz * 95.f, 0.f), 94.9999f);
  int ix = (int)x, iy = (int)y, iz = (int)z;
  float fx = x - ix, fy = y - iy, fz = z - iz;
  float acc[32];
  #pragma unroll
  for (int c = 0; c < 32; c++) acc[c] = 0.f;
  size_t cbase = ((size_t)(iz * GDIM + iy) * GDIM + ix) * 32;
  #pragma unroll
  for (int dz = 0; dz < 2; dz++)
  #pragma unroll
  for (int dy = 0; dy < 2; dy++)
  #pragma unroll
  for (int dx = 0; dx < 2; dx++){
    float w = (dx ? fx : 1.f - fx) * (dy ? fy : 1.f - fy) * (dz ? fz : 1.f - fz);
    const float4* cp = (const float4*)(vpk + cbase + ((size_t)(dz * GDIM + dy) * GDIM + dx) * 32);
    #pragma unroll
    for (int qq = 0; qq < 8; qq++){
      float4 v = cp[qq];
      acc[qq*4+0] += w * v.x; acc[qq*4+1] += w * v.y;
      acc[qq*4+2] += w * v.z; acc[qq*4+3] += w * v.w;
    }
  }
  float4* fp = (float4*)(feat + (size_t)idx * 32);
  #pragma unroll
  for (int qq = 0; qq < 8; qq++){
    float4 v = {acc[qq*4+0], acc[qq*4+1], acc[qq*4+2], acc[qq*4+3]};
    fp[qq] = v;
  }
}

// ---------------------------------------------------------------- fwd layer0, fp64: h0 = relu(x@W0+b0), mask0
// fp64 kept: h0 VALUES feed fwd1's near-zero sign decisions, so h0 must be
// fp64-value-accurate (round-4 lesson). LDS swizzled (k, j4, ng).
__launch_bounds__(256)
__global__ void k_fwd0(const float* __restrict__ pts, const float* __restrict__ feat,
                       const float* __restrict__ W0, const float* __restrict__ b0,
                       float* __restrict__ h0, uint16_t* __restrict__ mask0,
                       int base, int chunk){
  __shared__ float w0s[35 * 256];   // swizzled: [(k*4 + j4)*16 + ng] float4s
  __shared__ float xs[16][36];
  __shared__ float b0s[256];        // swizzled: [(j4*16 + ng)] float4s
  int tid = threadIdx.x;
  for (int i = tid; i < 35 * 256; i += 256){
    int k = i >> 8, n = i & 255;
    int ng = n >> 4, j4 = (n >> 2) & 3, e = n & 3;
    w0s[((k * 4 + j4) * 16 + ng) * 4 + e] = W0[i];
  }
  {
    int n = tid, ng = n >> 4, j4 = (n >> 2) & 3, e = n & 3;
    b0s[(j4 * 16 + ng) * 4 + e] = b0[n];
  }
  int p0 = blockIdx.x * 16;
  for (int i = tid; i < 16 * 35; i += 256){
    int p = i / 35, k = i - p * 35;
    float v;
    if (k < 3) v = pts[(size_t)(base + p0 + p) * 3 + k];
    else       v = feat[(size_t)(p0 + p) * 32 + (k - 3)];
    xs[p][k] = v;
  }
  __syncthreads();
  int p = tid >> 4, ng = tid & 15;
  const float4* w4 = (const float4*)w0s;
  const float4* b4 = (const float4*)b0s;
  double acc[16];
  #pragma unroll
  for (int j4 = 0; j4 < 4; j4++){
    float4 b = b4[j4 * 16 + ng];
    acc[j4*4+0] = (double)b.x;
    acc[j4*4+1] = (double)b.y;
    acc[j4*4+2] = (double)b.z;
    acc[j4*4+3] = (double)b.w;
  }
  for (int k = 0; k < 35; k++){
    double xv = (double)xs[p][k];
    #pragma unroll
    for (int j4 = 0; j4 < 4; j4++){
      float4 w = w4[(k * 4 + j4) * 16 + ng];
      acc[j4*4+0] += xv * (double)w.x;
      acc[j4*4+1] += xv * (double)w.y;
      acc[j4*4+2] += xv * (double)w.z;
      acc[j4*4+3] += xv * (double)w.w;
    }
  }
  uint32_t m = 0;
  float* hp = h0 + (size_t)(p0 + p) * 256 + ng * 16;
  #pragma unroll
  for (int j4 = 0; j4 < 4; j4++){
    float4 v;
    v.x = fmaxf((float)acc[j4*4+0], 0.f);
    v.y = fmaxf((float)acc[j4*4+1], 0.f);
    v.z = fmaxf((float)acc[j4*4+2], 0.f);
    v.w = fmaxf((float)acc[j4*4+3], 0.f);
    ((float4*)hp)[j4] = v;
  }
  #pragma unroll
  for (int j = 0; j < 16; j++) if (acc[j] > 0.0) m |= 1u << j;
  mask0[(size_t)(p0 + p) * 16 + ng] = (uint16_t)m;
}

// ---------------------------------------------------------------- FUSED: fwd1 + gemm_h + gemm_bwd2 + gemm_bwd1
// r10 diagnosis: VGPR_Count=68 with 64 regs of live A-frags => compiler
// spilled ah/al to scratch, reloading 256B/lane per nt -> ~1 GB scratch
// traffic/launch == the measured 166us. Fix: s-OUTER / nt-INNER register
// blocking: acc[16] (64 regs, compile-time indexed) accumulates while one
// A-frag pair (8 regs) streams per s. Per-accumulator MFMA sequence is
// exactly r3's {hh(s),lh(s),hl(s)}, s=0..7 -> bit-identical numerics.
// __launch_bounds__(256,4): cap 128 VGPR (LDS already caps 4 blocks/CU).
__launch_bounds__(256, 4)
__global__ void k_fused(const float* __restrict__ h0,
                        const uint16_t* __restrict__ W1FH, const uint16_t* __restrict__ W1FL,
                        const float* __restrict__ W1, const float* __restrict__ b1,
                        const uint16_t* __restrict__ W2p, const float* __restrict__ b2,
                        float* __restrict__ hout,
                        const uint16_t* __restrict__ W1Tp, const uint16_t* __restrict__ w2col,
                        const uint16_t* __restrict__ mask0,
                        const uint16_t* __restrict__ W0Tp, uint16_t* __restrict__ gx,
                        int chunk){
  __shared__ __align__(16) uint16_t hlds[4][16][280];
  int lane = threadIdx.x & 63, wv = threadIdx.x >> 6;
  int tile = blockIdx.x * 4 + wv;
  int q = lane >> 4, m = lane & 15;

  // ---- phase 2 (register-blocked): h1 preacts into acc[16]
  float4v acc[16];
  #pragma unroll
  for (int nt = 0; nt < 16; nt++){
    float bv = b1[nt * 16 + m];
    float4v t = {bv, bv, bv, bv};
    acc[nt] = t;
  }
  {
    const uint4* bh = (const uint4*)W1FH + lane;
    const uint4* bl = (const uint4*)W1FL + lane;
    const float* ap = h0 + ((size_t)(tile * 16 + m)) * 256 + 8 * q;
    for (int s = 0; s < 8; s++){
      float4 v0 = *(const float4*)(ap + 32 * s);
      float4 v1 = *(const float4*)(ap + 32 * s + 4);
      float f[8] = {v0.x, v0.y, v0.z, v0.w, v1.x, v1.y, v1.z, v1.w};
      union { uint16_t h[8]; uint4 u; } hh, ll;
      #pragma unroll
      for (int j = 0; j < 8; j++){
        uint16_t hb = f2bf(f[j]);
        hh.h[j] = hb;
        ll.h[j] = f2bf(f[j] - bf2f(hb));
      }
      uint4 ahs = hh.u, als = ll.u;
      #pragma unroll
      for (int nt = 0; nt < 16; nt++){
        uint4 BH = bh[(nt * 8 + s) * 64];
        uint4 BL = bl[(nt * 8 + s) * 64];
        acc[nt] = mfma16(ahs, BH, acc[nt]);   // hi*hi
        acc[nt] = mfma16(als, BH, acc[nt]);   // lo*hi
        acc[nt] = mfma16(ahs, BL, acc[nt]);   // hi*lo (lo*lo dropped; r3 numerics)
      }
    }
  }
  // fixup (rare, fp64-exact signs) + relu -> hlds
  #pragma unroll
  for (int nt = 0; nt < 16; nt++){
    #pragma unroll
    for (int r = 0; r < 4; r++){
      if (fabsf(acc[nt][r]) < 1e-5f){
        int prow = tile * 16 + 4 * q + r;
        int n = nt * 16 + m;
        double da = (double)b1[n];
        const float* hrow = h0 + (size_t)prow * 256;
        for (int k = 0; k < 256; k++)
          da += (double)hrow[k] * (double)W1[k * 256 + n];
        acc[nt][r] = (float)da;
      }
    }
    #pragma unroll
    for (int r = 0; r < 4; r++)
      hlds[wv][4 * q + r][nt * 16 + m] = f2bf(fmaxf(acc[nt][r], 0.f));
  }
  // readout h1 A-frags (wave-private LDS)
  uint4 af[8];
  #pragma unroll
  for (int s = 0; s < 8; s++)
    af[s] = *(const uint4*)&hlds[wv][m][32 * s + 8 * q];

  // ---- phase 3: h = h1 @ W2 + b2
  {
    const uint4* bp = (const uint4*)W2p + lane;
    float4v a0 = {0.f,0.f,0.f,0.f}, a1 = {0.f,0.f,0.f,0.f};
    #pragma unroll
    for (int s = 0; s < 4; s++){
      a0 = mfma16(af[s], bp[s * 64], a0);
      a1 = mfma16(af[(s + 4)], bp[(s + 4) * 64], a1);
    }
    float bv = b2[m];
    #pragma unroll
    for (int r = 0; r < 4; r++)
      hout[((size_t)(tile * 16 + 4 * q + r)) * 16 + m] = (a0[r] + a1[r]) + bv;
  }

  // ---- phase 4: masked A-frags (mask1 .* W2col)
  uint4 afm[8];
  {
    const uint4* wc = (const uint4*)w2col;
    #pragma unroll
    for (int s = 0; s < 8; s++){
      union { uint4 v; uint16_t h[8]; } a, w, o;
      a.v = af[s];
      w.v = wc[s * 4 + q];
      #pragma unroll
      for (int j = 0; j < 8; j++) o.h[j] = a.h[j] ? w.h[j] : (uint16_t)0;
      afm[s] = o.v;
    }
  }

  // ---- phase 5: g0 = mask0 .* (afm @ W1T) -> hlds -> g0 A-frags
  {
    const uint4* bp = (const uint4*)W1Tp + lane;
    for (int nt = 0; nt < 16; nt++){
      float4v a0 = {0.f,0.f,0.f,0.f}, a1 = {0.f,0.f,0.f,0.f};
      #pragma unroll
      for (int s = 0; s < 4; s++){
        a0 = mfma16(afm[s], bp[(nt * 8 + s) * 64], a0);
        a1 = mfma16(afm[s + 4], bp[(nt * 8 + s + 4) * 64], a1);
      }
      #pragma unroll
      for (int r = 0; r < 4; r++){
        uint16_t mw = mask0[((size_t)(tile * 16 + 4 * q + r)) * 16 + nt];
        float v = ((mw >> m) & 1) ? (a0[r] + a1[r]) : 0.f;
        hlds[wv][4 * q + r][nt * 16 + m] = f2bf(v);
      }
    }
  }
  uint4 gf[8];
  #pragma unroll
  for (int s = 0; s < 8; s++)
    gf[s] = *(const uint4*)&hlds[wv][m][32 * s + 8 * q];

  // ---- phase 6: gx = g0 @ W0T
  {
    const uint4* bp = (const uint4*)W0Tp + lane;
    for (int nt = 0; nt < 3; nt++){
      float4v a0 = {0.f,0.f,0.f,0.f}, a1 = {0.f,0.f,0.f,0.f};
      #pragma unroll
      for (int s = 0; s < 4; s++){
        a0 = mfma16(gf[s], bp[(nt * 8 + s) * 64], a0);
        a1 = mfma16(gf[s + 4], bp[(nt * 8 + s + 4) * 64], a1);
      }
      #pragma unroll
      for (int r = 0; r < 4; r++)
        gx[((size_t)(tile * 16 + 4 * q + r)) * 48 + nt * 16 + m] = f2bf(a0[r] + a1[r]);
    }
  }
}

// ---------------------------------------------------------------- K_grad: pos-grad + pointwise outputs + rgb_in A-frags
__global__ void k_grad(const float* __restrict__ pts, const float* __restrict__ dirs,
                       const float* __restrict__ deltas, const float* __restrict__ beta,
                       const float* __restrict__ variance, const float* __restrict__ vpk,
                       const uint16_t* __restrict__ gx, const float* __restrict__ feat,
                       const float* __restrict__ hrm, uint16_t* __restrict__ rgbinA,
                       float* __restrict__ out, int base, int chunk){
  int idx = blockIdx.x * 256 + threadIdx.x;
  if (idx >= chunk) return;
  int g = base + idx;
  union { uint16_t h[48]; uint4 q[6]; } gv;
  const uint4* gp = (const uint4*)(gx + (size_t)idx * 48);
  #pragma unroll
  for (int i = 0; i < 6; i++) gv.q[i] = gp[i];
  float gfeat[32];
  #pragma unroll
  for (int c = 0; c < 32; c++) gfeat[c] = bf2f(gv.h[3 + c]);

  float px = pts[(size_t)g * 3 + 0], py = pts[(size_t)g * 3 + 1], pz = pts[(size_t)g * 3 + 2];
  float x = fminf(fmaxf(px * 95.f, 0.f), 94.9999f);
  float y = fminf(fmaxf(py * 95.f, 0.f), 94.9999f);
  float z = fminf(fmaxf(pz * 95.f, 0.f), 94.9999f);
  int ix = (int)x, iy = (int)y, iz = (int)z;
  float fx = x - ix, fy = y - iy, fz = z - iz;
  size_t cbase = ((size_t)(iz * GDIM + iy) * GDIM + ix) * 32;
  float gsx = 0.f, gsy = 0.f, gsz = 0.f;
  #pragma unroll
  for (int dz = 0; dz < 2; dz++)
  #pragma unroll
  for (int dy = 0; dy < 2; dy++)
  #pragma unroll
  for (int dx = 0; dx < 2; dx++){
    const float4* cp = (const float4*)(vpk + cbase + ((size_t)(dz * GDIM + dy) * GDIM + dx) * 32);
    float sdot = 0.f;
    #pragma unroll
    for (int qq = 0; qq < 8; qq++){
      float4 v = cp[qq];
      sdot += gfeat[qq*4+0] * v.x + gfeat[qq*4+1] * v.y
            + gfeat[qq*4+2] * v.z + gfeat[qq*4+3] * v.w;
    }
    float wx = dx ? fx : 1.f - fx, wy = dy ? fy : 1.f - fy, wz = dz ? fz : 1.f - fz;
    gsx += sdot * (dx ? 1.f : -1.f) * wy * wz;
    gsy += sdot * wx * (dy ? 1.f : -1.f) * wz;
    gsz += sdot * wx * wy * (dz ? 1.f : -1.f);
  }
  float grx = bf2f(gv.h[0]) + 95.f * gsx;
  float gry = bf2f(gv.h[1]) + 95.f * gsy;
  float grz = bf2f(gv.h[2]) + 95.f * gsz;

  float* o_dens  = out + (size_t)3 * PTOT;
  float* o_sdf   = out + (size_t)4 * PTOT;
  float* o_grad  = out + (size_t)5 * PTOT;
  float* o_norm  = out + (size_t)8 * PTOT;
  float* o_alpha = out + (size_t)11 * PTOT;

  o_grad[(size_t)g * 3 + 0] = grx;
  o_grad[(size_t)g * 3 + 1] = gry;
  o_grad[(size_t)g * 3 + 2] = grz;
  float nn = sqrtf(grx * grx + gry * gry + grz * grz);
  float inv = 1.f / fmaxf(nn, 1e-12f);
  o_norm[(size_t)g * 3 + 0] = grx * inv;
  o_norm[(size_t)g * 3 + 1] = gry * inv;
  o_norm[(size_t)g * 3 + 2] = grz * inv;

  float sdf = hrm[(size_t)idx * 16];
  o_sdf[g] = sdf;
  float be = fabsf(beta[0]) + 1e-4f;
  float sgn = (sdf > 0.f) ? 1.f : ((sdf < 0.f) ? -1.f : 0.f);
  o_dens[g] = (0.5f + 0.5f * sgn * expm1f(-fabsf(sdf) / be)) / be;

  float dxr = dirs[(size_t)g * 3 + 0], dyr = dirs[(size_t)g * 3 + 1], dzr = dirs[(size_t)g * 3 + 2];
  float delta = deltas[g];
  float inv_s = expf(variance[0] * 10.f);
  inv_s = fminf(fmaxf(inv_s, 1e-6f), 1e6f);
  float tc = dxr * grx + dyr * gry + dzr * grz;
  float itc = -fmaxf(-tc, 0.f);
  float en = sdf + itc * delta * 0.5f;
  float ep = sdf - itc * delta * 0.5f;
  float pc = 1.f / (1.f + expf(-ep * inv_s));
  float nc = 1.f / (1.f + expf(-en * inv_s));
  float alpha = (pc - nc + 1e-5f) / (pc + 1e-5f);
  o_alpha[g] = fminf(fmaxf(alpha, 0.f), 1.f);

  // rgb_in = [p(3), grad(3), feat(32), geo(15), dir(3)] -> 56, pad 64, A-frag layout
  union { uint16_t h[64]; uint4 q[8]; } rv;
  #pragma unroll
  for (int i = 0; i < 64; i++) rv.h[i] = 0;
  rv.h[0] = f2bf(px); rv.h[1] = f2bf(py); rv.h[2] = f2bf(pz);
  rv.h[3] = f2bf(grx); rv.h[4] = f2bf(gry); rv.h[5] = f2bf(grz);
  const float4* fp = (const float4*)(feat + (size_t)idx * 32);
  #pragma unroll
  for (int qq = 0; qq < 8; qq++){
    float4 v = fp[qq];
    rv.h[6 + qq*4 + 0] = f2bf(v.x); rv.h[6 + qq*4 + 1] = f2bf(v.y);
    rv.h[6 + qq*4 + 2] = f2bf(v.z); rv.h[6 + qq*4 + 3] = f2bf(v.w);
  }
  #pragma unroll
  for (int j = 0; j < 15; j++) rv.h[38 + j] = f2bf(hrm[(size_t)idx * 16 + 1 + j]);
  rv.h[53] = f2bf(dxr); rv.h[54] = f2bf(dyr); rv.h[55] = f2bf(dzr);
  int tile = idx >> 4, m = idx & 15;
  #pragma unroll
  for (int g8 = 0; g8 < 8; g8++){
    int s = g8 >> 2, qq = g8 & 3;
    ((uint4*)rgbinA)[((size_t)(tile * 2 + s)) * 64 + m + 16 * qq] = rv.q[g8];
  }
}

// ---------------------------------------------------------------- rgb: hr = relu(rgb_in@Wr0+br0); rgb = sigmoid(hr@Wr1+br1)
__launch_bounds__(256)
__global__ void k_rgb(const uint16_t* __restrict__ rgbinA, const uint16_t* __restrict__ Wr0p,
                      const float* __restrict__ br0, const float* __restrict__ Wr1,
                      const float* __restrict__ br1, float* __restrict__ outrgb,
                      int base, int chunk){
  __shared__ __align__(16) uint16_t hr[64][280];
  __shared__ float wr1s[768];
  __shared__ float br1s[3];
  int t = threadIdx.x;
  for (int i = t; i < 768; i += 256) wr1s[i] = Wr1[i];
  if (t < 3) br1s[t] = br1[t];
  int lane = t & 63, wv = t >> 6;
  int tile = blockIdx.x * 4 + wv;
  int q = lane >> 4, nl = lane & 15;
  uint4 af[2];
  const uint4* ap = (const uint4*)rgbinA + (size_t)tile * 2 * 64 + lane;
  af[0] = ap[0]; af[1] = ap[64];
  const uint4* bp = (const uint4*)Wr0p + lane;
  for (int nt = 0; nt < 16; nt++){
    float4v a0 = {0.f, 0.f, 0.f, 0.f}, a1 = {0.f, 0.f, 0.f, 0.f};
    a0 = mfma16(af[0], bp[(nt * 2) * 64], a0);
    a1 = mfma16(af[1], bp[(nt * 2 + 1) * 64], a1);
    float bv = br0[nt * 16 + nl];
    #pragma unroll
    for (int r = 0; r < 4; r++)
      hr[wv * 16 + 4 * q + r][nt * 16 + nl] = f2bf(fmaxf((a0[r] + a1[r]) + bv, 0.f));
  }
  __syncthreads();
  if (t < 192){
    int lp = t / 3, ch = t - lp * 3;
    float acc2 = 0.f;
    for (int u = 0; u < 256; u++) acc2 += bf2f(hr[lp][u]) * wr1s[u * 3 + ch];
    acc2 += br1s[ch];
    float val = 1.f / (1.f + expf(-acc2));
    outrgb[(size_t)(base + blockIdx.x * 64 + lp) * 3 + ch] = val;
  }
}

// ----------------------------------------------------------------
extern "C" void kernel_launch(void* const* d_in, const int* in_sizes, int n_in,
                              void* d_out, int out_size, void* d_ws, size_t ws_size,
                              hipStream_t stream){
  const float* pts      = (const float*)d_in[0];
  const float* dirs     = (const float*)d_in[1];
  const float* deltas   = (const float*)d_in[2];
  const float* vol0     = (const float*)d_in[3];
  const float* vol1     = (const float*)d_in[4];
  const float* W0       = (const float*)d_in[5];
  const float* b0       = (const float*)d_in[6];
  const float* W1       = (const float*)d_in[7];
  const float* b1       = (const float*)d_in[8];
  const float* W2       = (const float*)d_in[9];
  const float* b2       = (const float*)d_in[10];
  const float* Wr0      = (const float*)d_in[11];
  const float* br0      = (const float*)d_in[12];
  const float* Wr1      = (const float*)d_in[13];
  const float* br1      = (const float*)d_in[14];
  const float* beta     = (const float*)d_in[15];
  const float* variance = (const float*)d_in[16];
  float* out = (float*)d_out;
  char* ws = (char*)d_ws;

  size_t off = 0;
  auto alloc = [&](size_t b){ size_t o = off; off += (b + 255) & ~(size_t)255; return o; };
  size_t o_vpk  = alloc((size_t)VS * 32 * 4);   // fp32 voxel-major volumes (113 MB)
  size_t o_w2p  = alloc(8192);
  size_t o_w1tp = alloc(131072);
  size_t o_w0tp = alloc(24576);
  size_t o_wr0p = alloc(32768);
  size_t o_w2c  = alloc(512);
  size_t o_w1fh = alloc(131072);                // W1 forward B-frags, hi bf16
  size_t o_w1fl = alloc(131072);                // W1 forward B-frags, lo bf16
  size_t fixed = off;

  // per-point: feat 128 + h0 1024 + mask 32 + rgbinA 512 + gx 96 + hbuf 64 = 1856 B
  const int cands[7] = {262144, 131072, 65536, 32768, 16384, 8192, 4096};
  int chunk = 2048;
  for (int i = 0; i < 7; i++){
    if (fixed + (size_t)cands[i] * 1880 <= ws_size){ chunk = cands[i]; break; }
  }
  size_t o_feat = alloc((size_t)chunk * 128);
  size_t o_h0   = alloc((size_t)chunk * 1024);  // f32 h0
  size_t o_mask = alloc((size_t)chunk * 32);
  size_t o_h1A  = alloc((size_t)chunk * 512);   // rgbinA (h1A never goes to memory now)
  size_t o_gx   = alloc((size_t)chunk * 96);
  size_t o_h    = alloc((size_t)chunk * 64);

  float*    vpk  = (float*)(ws + o_vpk);
  uint16_t* w2p  = (uint16_t*)(ws + o_w2p);
  uint16_t* w1tp = (uint16_t*)(ws + o_w1tp);
  uint16_t* w0tp = (uint16_t*)(ws + o_w0tp);
  uint16_t* wr0p = (uint16_t*)(ws + o_wr0p);
  uint16_t* w2c  = (uint16_t*)(ws + o_w2c);
  uint16_t* w1fh = (uint16_t*)(ws + o_w1fh);
  uint16_t* w1fl = (uint16_t*)(ws + o_w1fl);
  float*    feat = (float*)(ws + o_feat);
  float*    h0   = (float*)(ws + o_h0);
  uint16_t* mask = (uint16_t*)(ws + o_mask);
  uint16_t* rgbinA = (uint16_t*)(ws + o_h1A);
  uint16_t* gx   = (uint16_t*)(ws + o_gx);
  float*    hbuf = (float*)(ws + o_h);

  k_pack_vol<<<(VS + 255) / 256, 256, 0, stream>>>(vol0, vol1, vpk);
  k_pack_w<<<321, 64, 0, stream>>>(W0, W1, W2, Wr0, w2p, w1tp, w0tp, wr0p, w2c, w1fh, w1fl);

  int nchunks = PTOT / chunk;
  for (int c = 0; c < nchunks; c++){
    int basep = c * chunk;
    k_sample<<<chunk / 256, 256, 0, stream>>>(pts, vpk, feat, basep, chunk);
    k_fwd0<<<chunk / 16, 256, 0, stream>>>(pts, feat, W0, b0, h0, mask, basep, chunk);
    k_fused<<<chunk / 64, 256, 0, stream>>>(h0, w1fh, w1fl, W1, b1,
                                            w2p, b2, hbuf,
                                            w1tp, w2c, mask,
                                            w0tp, gx, chunk);
    k_grad<<<chunk / 256, 256, 0, stream>>>(pts, dirs, deltas, beta, variance, vpk,
                                            gx, feat, hbuf, rgbinA, out, basep, chunk);
    k_rgb<<<chunk / 64, 256, 0, stream>>>(rgbinA, wr0p, br0, Wr1, br1, out, basep, chunk);
  }
}